// Round 6
// baseline (570.722 us; speedup 1.0000x reference)
//
#include <hip/hip_runtime.h>
#include <stdint.h>

typedef unsigned char u8;
typedef unsigned short u16;
typedef unsigned int u32;
typedef __attribute__((ext_vector_type(8))) short short8;
typedef __attribute__((ext_vector_type(4))) float floatx4;

#define BN_EPS 1e-5f
#define NPB 64        // nodes per bucket (power of 2; bucket = dst >> NPB_SHIFT)
#define NPB_SHIFT 6
#define NBMAX 2048

__device__ __forceinline__ float bf2f(u16 u) { return __uint_as_float(((unsigned)u) << 16); }
__device__ __forceinline__ u16 f2bf(float f) {
  unsigned u = __float_as_uint(f);
  u += 0x7FFFu + ((u >> 16) & 1u);   // round-to-nearest-even
  return (u16)(u >> 16);
}

// ---------------------------------------------------------------------------
// zero the small control block (stats + bucket totals)
__global__ void k_init(float* __restrict__ stats, u32* __restrict__ bucketTotal) {
  for (int i = threadIdx.x; i < 1024; i += blockDim.x) stats[i] = 0.f;
  for (int i = threadIdx.x; i < NBMAX + 1; i += blockDim.x) bucketTotal[i] = 0u;
}

// ---------------------------------------------------------------------------
// fused: global sum-of-squares of directions + per-bucket dst histogram
__global__ void k_norm_hist(const int* __restrict__ ei, const float* __restrict__ pos,
                            int E, int NB, float* __restrict__ stats,
                            u32* __restrict__ bucketTotal) {
  __shared__ u32 lh[NBMAX];
  __shared__ float red[16];
  for (int i = threadIdx.x; i < NB; i += blockDim.x) lh[i] = 0u;
  __syncthreads();
  int tid = blockIdx.x * blockDim.x + threadIdx.x;
  int stride = gridDim.x * blockDim.x;
  float acc = 0.f;
  for (int e = tid; e < E; e += stride) {
    int s = ei[e], d = ei[E + e];
    float d0 = pos[3 * s + 0] - pos[3 * d + 0];
    float d1 = pos[3 * s + 1] - pos[3 * d + 1];
    float d2 = pos[3 * s + 2] - pos[3 * d + 2];
    acc = fmaf(d0, d0, acc);
    acc = fmaf(d1, d1, acc);
    acc = fmaf(d2, d2, acc);
    atomicAdd(&lh[d >> NPB_SHIFT], 1u);
  }
#pragma unroll
  for (int off = 32; off > 0; off >>= 1) acc += __shfl_down(acc, off, 64);
  if ((threadIdx.x & 63) == 0) red[threadIdx.x >> 6] = acc;
  __syncthreads();
  if (threadIdx.x == 0) {
    float s = 0.f;
    for (int w = 0; w < (int)(blockDim.x >> 6); w++) s += red[w];
    atomicAdd(&stats[0], s);
  }
  for (int i = threadIdx.x; i < NB; i += blockDim.x)
    if (lh[i]) atomicAdd(&bucketTotal[i], lh[i]);
}

// ---------------------------------------------------------------------------
// exclusive scan of bucket totals — single wave, shfl prefix scan
__global__ void k_scan(const u32* __restrict__ bucketTotal, u32* __restrict__ base,
                       u32* __restrict__ cursor, int NB) {
  int lane = threadIdx.x;  // launched with 64 threads, 1 block
  u32 run = 0;
  for (int b0 = 0; b0 < NB; b0 += 64) {
    int b = b0 + lane;
    u32 v = (b < NB) ? bucketTotal[b] : 0u;
    u32 s = v;
#pragma unroll
    for (int off = 1; off < 64; off <<= 1) {
      u32 t = __shfl_up(s, off, 64);
      if (lane >= off) s += t;
    }
    u32 excl = run + s - v;
    if (b < NB) { base[b] = excl; cursor[b] = excl; }
    run += __shfl(s, 63, 64);   // broadcast chunk total
  }
  if (lane == 0) base[NB] = run;
}

// ---------------------------------------------------------------------------
// bin edges by dst bucket: sorted2[slot] = {src, dst} (coalesced-consumable
// by layer1) + ln8[slot] = dst & 63 (compact lane id for layer3max).
__global__ void k_place(const int* __restrict__ ei, int E, int NB,
                        u32* __restrict__ cursor, uint2* __restrict__ sorted2,
                        u8* __restrict__ ln8) {
  __shared__ u32 lh[NBMAX];
  __shared__ u32 lbase[NBMAX];
  for (int i = threadIdx.x; i < NB; i += blockDim.x) lh[i] = 0u;
  __syncthreads();
  int tid = blockIdx.x * blockDim.x + threadIdx.x;
  int stride = gridDim.x * blockDim.x;
  for (int e = tid; e < E; e += stride) atomicAdd(&lh[ei[E + e] >> NPB_SHIFT], 1u);
  __syncthreads();
  for (int i = threadIdx.x; i < NB; i += blockDim.x) {
    u32 c = lh[i];
    lbase[i] = c ? atomicAdd(&cursor[i], c) : 0u;
    lh[i] = 0u;
  }
  __syncthreads();
  for (int e = tid; e < E; e += stride) {
    int s = ei[e];
    int d = ei[E + e];
    int b = d >> NPB_SHIFT;
    u32 slot = lbase[b] + atomicAdd(&lh[b], 1u);
    sorted2[slot] = make_uint2((u32)s, (u32)d);
    ln8[slot] = (u8)(d & (NPB - 1));
  }
}

// ---------------------------------------------------------------------------
// layer 1, two-phase, slot-ordered: phase A reads sorted2 COALESCED and
// gathers pos/x (1.2 MB each, L2-resident); phase B = wave per edge from LDS.
// h written in sorted-slot order -> all downstream h traffic is streaming.
__global__ __launch_bounds__(256) void k_layer1(
    const int* __restrict__ ei, const float* __restrict__ pos,
    const float* __restrict__ x, const float* __restrict__ W1,
    const float* __restrict__ b1, u16* __restrict__ h,
    const float* __restrict__ stats, float* __restrict__ gsum,
    float* __restrict__ gsq, int E, const uint2* __restrict__ sorted2) {
  __shared__ float in6[6][256];
  __shared__ float ssum[64], ssq[64];
  float invn = 1.0f / sqrtf(stats[0]);
  int t = threadIdx.x;
  int lane = t & 63;
  int wv = t >> 6;
  float w[6];
#pragma unroll
  for (int k = 0; k < 6; k++) w[k] = W1[k * 64 + lane];
  float bias = b1[lane];
  float psum = 0.f, psq = 0.f;

  int chunks = (E + 255) >> 8;
  for (int c = blockIdx.x; c < chunks; c += gridDim.x) {
    long e0 = (long)c << 8;
    int e = (int)e0 + t;   // slot id
    float v[6] = {0.f, 0.f, 0.f, 0.f, 0.f, 0.f};
    if (e < E) {
      int s, d;
      if (sorted2) {
        uint2 sd = sorted2[e];
        s = (int)sd.x;
        d = (int)sd.y;
      } else {
        s = ei[e];
        d = ei[E + e];
      }
      float p0 = pos[3 * s + 0], p1 = pos[3 * s + 1], p2 = pos[3 * s + 2];
      float q0 = pos[3 * d + 0], q1 = pos[3 * d + 1], q2 = pos[3 * d + 2];
      v[0] = (p0 - q0) * invn;
      v[1] = (p1 - q1) * invn;
      v[2] = (p2 - q2) * invn;
      v[3] = x[3 * d + 0];
      v[4] = x[3 * d + 1];
      v[5] = x[3 * d + 2];
    }
    __syncthreads();  // previous chunk's phase-B reads done
#pragma unroll
    for (int k = 0; k < 6; k++) in6[k][t] = v[k];
    __syncthreads();
    int lim = E - (int)e0;
    if (lim > 256) lim = 256;
    int base = wv * 64;
#pragma unroll 4
    for (int i = 0; i < 64; i++) {
      int el = base + i;
      if (el >= lim) break;
      float acc = bias;
#pragma unroll
      for (int k = 0; k < 6; k++) acc = fmaf(in6[k][el], w[k], acc);
      acc = fmaxf(acc, 0.f);
      u16 hb = f2bf(acc);
      h[(e0 + el) * 64 + lane] = hb;
      float hf = bf2f(hb);
      psum += hf;
      psq = fmaf(hf, hf, psq);
    }
  }
  if (t < 64) { ssum[t] = 0.f; ssq[t] = 0.f; }
  __syncthreads();
  atomicAdd(&ssum[lane], psum);
  atomicAdd(&ssq[lane], psq);
  __syncthreads();
  if (t < 64) {
    atomicAdd(&gsum[t], ssum[t]);
    atomicAdd(&gsq[t], ssq[t]);
  }
}

// ---------------------------------------------------------------------------
// layer 2: h = relu( bn_in(h) @ W + b ), in place. BN finalize computed in a
// 64-thread prologue from gsum/gsq, folded into W' = sc_in*W and
// bias' = b + sh_in^T W, so A-frags are RAW uint4 loads.
__global__ __launch_bounds__(256) void k_layer_mfma(
    u16* h, const float* __restrict__ W, const float* __restrict__ b,
    const float* __restrict__ gsum_in, const float* __restrict__ gsq_in,
    const float* __restrict__ g_in, const float* __restrict__ be_in, float invE,
    float* __restrict__ gsum, float* __restrict__ gsq, int E) {
  __shared__ float sc_s[64], sh_s[64];
  if (threadIdx.x < 64) {
    int c = threadIdx.x;
    float mu = gsum_in[c] * invE;
    float var = gsq_in[c] * invE - mu * mu;
    float s = g_in[c] * rsqrtf(var + BN_EPS);
    sc_s[c] = s;
    sh_s[c] = be_in[c] - mu * s;
  }
  __syncthreads();

  int lane = threadIdx.x & 63;
  int m = lane & 15;
  int q = lane >> 4;

  short8 bf[4][2];
  float bias[4];
#pragma unroll
  for (int t = 0; t < 4; t++) {
    int n = t * 16 + m;
    float bb = b[n];
    for (int k = 0; k < 64; k++) bb = fmaf(sh_s[k], W[k * 64 + n], bb);
    bias[t] = bb;
#pragma unroll
    for (int s = 0; s < 2; s++)
#pragma unroll
      for (int j = 0; j < 8; j++) {
        int k = s * 32 + q * 8 + j;
        bf[t][s][j] = (short)f2bf(W[k * 64 + n] * sc_s[k]);
      }
  }

  float psum[4] = {0.f, 0.f, 0.f, 0.f}, psq[4] = {0.f, 0.f, 0.f, 0.f};

  int tiles = E >> 4;
  int gw = ((int)blockIdx.x * (blockDim.x >> 6)) + (threadIdx.x >> 6);
  int nw = (int)gridDim.x * (blockDim.x >> 6);

  for (int tile = gw; tile < tiles; tile += nw) {
    long e0 = (long)tile * 16;
    const u16* rowp = h + (e0 + m) * 64 + q * 8;
    short8 a0 = *(const short8*)(rowp);
    short8 a1 = *(const short8*)(rowp + 32);
    floatx4 acc[4];
#pragma unroll
    for (int t = 0; t < 4; t++) acc[t] = (floatx4){0.f, 0.f, 0.f, 0.f};
#pragma unroll
    for (int t = 0; t < 4; t++)
      acc[t] = __builtin_amdgcn_mfma_f32_16x16x32_bf16(a0, bf[t][0], acc[t], 0, 0, 0);
#pragma unroll
    for (int t = 0; t < 4; t++)
      acc[t] = __builtin_amdgcn_mfma_f32_16x16x32_bf16(a1, bf[t][1], acc[t], 0, 0, 0);

#pragma unroll
    for (int t = 0; t < 4; t++) {
#pragma unroll
      for (int r = 0; r < 4; r++) {
        float v = acc[t][r] + bias[t];
        v = fmaxf(v, 0.f);
        u16 hb = f2bf(v);
        h[(e0 + q * 4 + r) * 64 + t * 16 + m] = hb;
        float hf = bf2f(hb);
        psum[t] += hf;
        psq[t] = fmaf(hf, hf, psq[t]);
      }
    }
  }

#pragma unroll
  for (int t = 0; t < 4; t++) {
    psum[t] += __shfl_xor(psum[t], 16, 64);
    psum[t] += __shfl_xor(psum[t], 32, 64);
    psq[t] += __shfl_xor(psq[t], 16, 64);
    psq[t] += __shfl_xor(psq[t], 32, 64);
  }
  __shared__ float ssum[64], ssq[64];
  if (threadIdx.x < 64) { ssum[threadIdx.x] = 0.f; ssq[threadIdx.x] = 0.f; }
  __syncthreads();
  if (q == 0) {
#pragma unroll
    for (int t = 0; t < 4; t++) {
      atomicAdd(&ssum[t * 16 + m], psum[t]);
      atomicAdd(&ssq[t * 16 + m], psq[t]);
    }
  }
  __syncthreads();
  if (threadIdx.x < 64) {
    atomicAdd(&gsum[threadIdx.x], ssum[threadIdx.x]);
    atomicAdd(&gsq[threadIdx.x], ssq[threadIdx.x]);
  }
}

// ---------------------------------------------------------------------------
// FUSED layer 3 + scatter-max, per-bucket, PREFETCHED: one block per bucket,
// 4 waves stride the bucket's contiguous tile range. Next tile's A-frags and
// lane ids are loaded into registers BEFORE the current tile's MFMA+epilogue
// (covers ~500-900cy HBM latency; r3's version lacked this and stalled).
// acc -> raw-bf16 XOR-masked keys -> LDS atomicMax (stride-65 tile; register
// pre-reduce over consecutive same-node rows), stats3 accumulated, raw key
// tile written to outk. h3 never touches HBM (~400 MB removed vs split).
__global__ __launch_bounds__(256) void k_layer3max(
    const u16* __restrict__ h, const u8* __restrict__ ln8,
    const u32* __restrict__ base, const float* __restrict__ W,
    const float* __restrict__ b, const float* __restrict__ gsum_in,
    const float* __restrict__ gsq_in, const float* __restrict__ g_in,
    const float* __restrict__ be_in, float invE, float* __restrict__ gsum,
    float* __restrict__ gsq, const float* __restrict__ g3,
    u32* __restrict__ outk, int N) {
  __shared__ float sc_s[64], sh_s[64];
  __shared__ u32 tile[64 * 65];  // stride 65: bank = (ln + c) & 31
  __shared__ float ssum[64], ssq[64];
  if (threadIdx.x < 64) {
    int c = threadIdx.x;
    float mu = gsum_in[c] * invE;
    float var = gsq_in[c] * invE - mu * mu;
    float s = g_in[c] * rsqrtf(var + BN_EPS);
    sc_s[c] = s;
    sh_s[c] = be_in[c] - mu * s;
    ssum[c] = 0.f;
    ssq[c] = 0.f;
  }
  for (int i = threadIdx.x; i < 64 * 65; i += blockDim.x) tile[i] = 0u;
  __syncthreads();

  int lane = threadIdx.x & 63;
  int m = lane & 15;
  int q = lane >> 4;
  int wv = threadIdx.x >> 6;

  short8 bf[4][2];
  float bias[4];
  u32 xmask[4];
#pragma unroll
  for (int t = 0; t < 4; t++) {
    int n = t * 16 + m;
    float bb = b[n];
    for (int k = 0; k < 64; k++) bb = fmaf(sh_s[k], W[k * 64 + n], bb);
    bias[t] = bb;
    xmask[t] = (g3[n] < 0.f) ? 0xFFFFu : 0u;
#pragma unroll
    for (int s = 0; s < 2; s++)
#pragma unroll
      for (int j = 0; j < 8; j++) {
        int k = s * 32 + q * 8 + j;
        bf[t][s][j] = (short)f2bf(W[k * 64 + n] * sc_s[k]);
      }
  }

  int bb_ = blockIdx.x;
  int start = (int)base[bb_];
  int end = (int)base[bb_ + 1];
  float psum[4] = {0.f, 0.f, 0.f, 0.f}, psq[4] = {0.f, 0.f, 0.f, 0.f};

  int i0 = start + wv * 16;
  short8 a0 = {0, 0, 0, 0, 0, 0, 0, 0}, a1 = {0, 0, 0, 0, 0, 0, 0, 0};
  short8 a0n = {0, 0, 0, 0, 0, 0, 0, 0}, a1n = {0, 0, 0, 0, 0, 0, 0, 0};
  u32 lnr[4] = {0xFFFFFFFFu, 0xFFFFFFFFu, 0xFFFFFFFFu, 0xFFFFFFFFu};
  u32 lnrn[4] = {0xFFFFFFFFu, 0xFFFFFFFFu, 0xFFFFFFFFu, 0xFFFFFFFFu};
  if (i0 < end) {
    long rr = i0 + m;
    if (rr > end - 1) rr = end - 1;
    const u16* rowp = h + rr * 64 + q * 8;
    a0 = *(const short8*)(rowp);
    a1 = *(const short8*)(rowp + 32);
#pragma unroll
    for (int r = 0; r < 4; r++) {
      int sl = i0 + q * 4 + r;
      lnr[r] = (sl < end) ? (u32)ln8[sl] : 0xFFFFFFFFu;
    }
  }

  for (; i0 < end; i0 += 64) {
    int i0n = i0 + 64;
    if (i0n < end) {  // prefetch next tile (consumed next iteration)
      long rr = i0n + m;
      if (rr > end - 1) rr = end - 1;
      const u16* rowp = h + rr * 64 + q * 8;
      a0n = *(const short8*)(rowp);
      a1n = *(const short8*)(rowp + 32);
#pragma unroll
      for (int r = 0; r < 4; r++) {
        int sl = i0n + q * 4 + r;
        lnrn[r] = (sl < end) ? (u32)ln8[sl] : 0xFFFFFFFFu;
      }
    }

    floatx4 acc[4];
#pragma unroll
    for (int t = 0; t < 4; t++) acc[t] = (floatx4){0.f, 0.f, 0.f, 0.f};
#pragma unroll
    for (int t = 0; t < 4; t++)
      acc[t] = __builtin_amdgcn_mfma_f32_16x16x32_bf16(a0, bf[t][0], acc[t], 0, 0, 0);
#pragma unroll
    for (int t = 0; t < 4; t++)
      acc[t] = __builtin_amdgcn_mfma_f32_16x16x32_bf16(a1, bf[t][1], acc[t], 0, 0, 0);

#pragma unroll
    for (int t = 0; t < 4; t++) {
      int c = t * 16 + m;
      u32 curln = 0xFFFFFFFFu, curkey = 0u;
#pragma unroll
      for (int r = 0; r < 4; r++) {
        if (lnr[r] == 0xFFFFFFFFu) continue;
        float v = acc[t][r] + bias[t];
        v = fmaxf(v, 0.f);
        u16 hb = f2bf(v);
        float hf = bf2f(hb);
        psum[t] += hf;
        psq[t] = fmaf(hf, hf, psq[t]);
        u32 key = ((u32)hb ^ xmask[t]) | 0x10000u;
        if (lnr[r] == curln) {
          curkey = key > curkey ? key : curkey;
        } else {
          if (curln != 0xFFFFFFFFu) atomicMax(&tile[curln * 65 + c], curkey);
          curln = lnr[r];
          curkey = key;
        }
      }
      if (curln != 0xFFFFFFFFu) atomicMax(&tile[curln * 65 + c], curkey);
    }

    a0 = a0n;
    a1 = a1n;
#pragma unroll
    for (int r = 0; r < 4; r++) lnr[r] = lnrn[r];
  }

  // stats reduce
#pragma unroll
  for (int t = 0; t < 4; t++) {
    psum[t] += __shfl_xor(psum[t], 16, 64);
    psum[t] += __shfl_xor(psum[t], 32, 64);
    psq[t] += __shfl_xor(psq[t], 16, 64);
    psq[t] += __shfl_xor(psq[t], 32, 64);
  }
  __syncthreads();
  if (q == 0) {
#pragma unroll
    for (int t = 0; t < 4; t++) {
      atomicAdd(&ssum[t * 16 + m], psum[t]);
      atomicAdd(&ssq[t * 16 + m], psq[t]);
    }
  }
  __syncthreads();
  if (threadIdx.x < 64) {
    if (ssum[threadIdx.x] != 0.f) atomicAdd(&gsum[threadIdx.x], ssum[threadIdx.x]);
    if (ssq[threadIdx.x] != 0.f) atomicAdd(&gsq[threadIdx.x], ssq[threadIdx.x]);
  }
  // coalesced raw-key tile write (empty nodes keep key 0)
  int node0 = bb_ * NPB;
  for (int l = threadIdx.x; l < NPB * 64; l += blockDim.x) {
    int node = node0 + (l >> 6);
    if (node < N) outk[(long)node * 64 + (l & 63)] = tile[(l >> 6) * 65 + (l & 63)];
  }
}

// ---------------------------------------------------------------------------
// apply BN3 to the key tiles once stats3 are complete; key 0 == empty -> 0
__global__ void k_final(u32* __restrict__ outk, const float* __restrict__ gsum3,
                        const float* __restrict__ gsq3, const float* __restrict__ g3,
                        const float* __restrict__ be3, float invE, long n) {
  int c = threadIdx.x & 63;  // blockDim multiple of 64 keeps channel fixed
  float mu = gsum3[c] * invE;
  float var = gsq3[c] * invE - mu * mu;
  float sc = g3[c] * rsqrtf(var + BN_EPS);
  float sh = be3[c] - mu * sc;
  u32 me = (g3[c] < 0.f) ? 0xFFFFu : 0u;
  long i = (long)blockIdx.x * blockDim.x + threadIdx.x;
  long stride = (long)gridDim.x * blockDim.x;
  for (long j = i; j < n; j += stride) {
    u32 k = outk[j];
    float v = (k == 0u) ? 0.f : fmaf(bf2f((u16)((k & 0xFFFFu) ^ me)), sc, sh);
    ((float*)outk)[j] = v;
  }
}

// ---------------------------------------------------------------------------
// fallback path kernels (only if ws too small): -inf init, atomic scatter, fixup
__global__ void k_initout(float* __restrict__ outf, long n, float* __restrict__ stats,
                          u32* __restrict__ bucketTotal) {
  long i = (long)blockIdx.x * blockDim.x + threadIdx.x;
  long stride = (long)gridDim.x * blockDim.x;
  for (long j = i; j < n; j += stride) outf[j] = __uint_as_float(0xFF800000u);
  if (i < 1024) stats[i] = 0.f;
  if (i < NBMAX + 1) bucketTotal[i] = 0u;
}
__global__ void k_scatter(const int* __restrict__ ei, const u16* __restrict__ h,
                          const float* __restrict__ gsum3, const float* __restrict__ gsq3,
                          const float* __restrict__ g3, const float* __restrict__ be3,
                          float invE, float* outf, int E) {
  int lane = threadIdx.x & 63;
  int gw = ((int)blockIdx.x * (blockDim.x >> 6)) + (threadIdx.x >> 6);
  int nw = (int)gridDim.x * (blockDim.x >> 6);
  float mu = gsum3[lane] * invE;
  float var = gsq3[lane] * invE - mu * mu;
  float sc = g3[lane] * rsqrtf(var + BN_EPS);
  float sh = be3[lane] - mu * sc;
  for (int e = gw; e < E; e += nw) {
    int d = ei[E + e];
    float v = fmaf(bf2f(h[(long)e * 64 + lane]), sc, sh);
    float* addr = outf + (long)d * 64 + lane;
    if (v >= 0.f)
      atomicMax((int*)addr, __float_as_int(v));
    else
      atomicMin((unsigned int*)addr, __float_as_uint(v));
  }
}
__global__ void k_out(float* __restrict__ outf, long n) {
  long i = (long)blockIdx.x * blockDim.x + threadIdx.x;
  long stride = (long)gridDim.x * blockDim.x;
  for (long j = i; j < n; j += stride) {
    float v = outf[j];
    unsigned u = __float_as_uint(v);
    if ((u & 0x7F800000u) == 0x7F800000u) v = 0.f;
    outf[j] = v;
  }
}

// ---------------------------------------------------------------------------
extern "C" void kernel_launch(void* const* d_in, const int* in_sizes, int n_in,
                              void* d_out, int out_size, void* d_ws, size_t ws_size,
                              hipStream_t stream) {
  const float* x = (const float*)d_in[0];
  const float* pos = (const float*)d_in[1];
  const int* ei = (const int*)d_in[2];
  const float* W1 = (const float*)d_in[3];
  const float* b1 = (const float*)d_in[4];
  const float* g1 = (const float*)d_in[5];
  const float* be1 = (const float*)d_in[6];
  const float* W2 = (const float*)d_in[7];
  const float* b2 = (const float*)d_in[8];
  const float* g2 = (const float*)d_in[9];
  const float* be2 = (const float*)d_in[10];
  const float* W3 = (const float*)d_in[11];
  const float* b3 = (const float*)d_in[12];
  const float* g3 = (const float*)d_in[13];
  const float* be3 = (const float*)d_in[14];

  int N = in_sizes[0] / 3;
  int E = in_sizes[2] / 2;
  int NB = (N + NPB - 1) / NPB;
  long n_out = (long)N * 64;

  char* wsb = (char*)d_ws;
  u16* h = (u16*)wsb;  // [E,64] bf16 activations, in sorted-slot order
  size_t off = (size_t)E * 64 * 2;
  float* stats = (float*)(wsb + off);
  off += 1024 * 4;
  u32* bucketTotal = (u32*)(wsb + off);
  off += (NBMAX + 1) * 4;
  u32* baseArr = (u32*)(wsb + off);
  off += (NBMAX + 1) * 4;
  u32* cursor = (u32*)(wsb + off);
  off += NBMAX * 4;
  off = (off + 7) & ~(size_t)7;  // 8-align for uint2
  uint2* sorted2 = (uint2*)(wsb + off);
  off += (size_t)E * 8;
  u8* ln8 = (u8*)(wsb + off);
  off += (size_t)E;
  size_t need = off;

  float* gsum1 = stats + 64, * gsq1 = stats + 128;
  float* gsum2 = stats + 192, * gsq2 = stats + 256;
  float* gsum3 = stats + 320, * gsq3 = stats + 384;

  float* outf = (float*)d_out;
  float invE = 1.0f / (float)E;
  bool binned = (ws_size >= need) && (NB <= NBMAX);

  if (binned) {
    k_init<<<1, 1024, 0, stream>>>(stats, bucketTotal);
    k_norm_hist<<<256, 256, 0, stream>>>(ei, pos, E, NB, stats, bucketTotal);
    k_scan<<<1, 64, 0, stream>>>(bucketTotal, baseArr, cursor, NB);
    k_place<<<256, 256, 0, stream>>>(ei, E, NB, cursor, sorted2, ln8);
    k_layer1<<<1024, 256, 0, stream>>>(ei, pos, x, W1, b1, h, stats, gsum1, gsq1, E, sorted2);
    k_layer_mfma<<<1024, 256, 0, stream>>>(h, W2, b2, gsum1, gsq1, g1, be1, invE, gsum2, gsq2, E);
    k_layer3max<<<NB, 256, 0, stream>>>(h, ln8, baseArr, W3, b3, gsum2, gsq2, g2, be2,
                                        invE, gsum3, gsq3, g3, (u32*)outf, N);
    k_final<<<1024, 256, 0, stream>>>((u32*)outf, gsum3, gsq3, g3, be3, invE, n_out);
  } else {
    k_initout<<<4096, 256, 0, stream>>>(outf, n_out, stats, bucketTotal);
    k_norm_hist<<<256, 256, 0, stream>>>(ei, pos, E, NB <= NBMAX ? NB : 1, stats, bucketTotal);
    k_layer1<<<1024, 256, 0, stream>>>(ei, pos, x, W1, b1, h, stats, gsum1, gsq1, E, (const uint2*)nullptr);
    k_layer_mfma<<<1024, 256, 0, stream>>>(h, W2, b2, gsum1, gsq1, g1, be1, invE, gsum2, gsq2, E);
    k_layer_mfma<<<1024, 256, 0, stream>>>(h, W3, b3, gsum2, gsq2, g2, be2, invE, gsum3, gsq3, E);
    k_scatter<<<2048, 256, 0, stream>>>(ei, h, gsum3, gsq3, g3, be3, invE, outf, E);
    k_out<<<2048, 256, 0, stream>>>(outf, n_out);
  }
}

// Round 7
// 523.215 us; speedup vs baseline: 1.0908x; 1.0908x over previous
//
#include <hip/hip_runtime.h>
#include <stdint.h>

typedef unsigned char u8;
typedef unsigned short u16;
typedef unsigned int u32;
typedef __attribute__((ext_vector_type(8))) short short8;
typedef __attribute__((ext_vector_type(4))) float floatx4;

#define BN_EPS 1e-5f
#define NPB 64        // nodes per bucket (power of 2; bucket = dst >> NPB_SHIFT)
#define NPB_SHIFT 6
#define NBMAX 2048

__device__ __forceinline__ float bf2f(u16 u) { return __uint_as_float(((unsigned)u) << 16); }
__device__ __forceinline__ u16 f2bf(float f) {
  unsigned u = __float_as_uint(f);
  u += 0x7FFFu + ((u >> 16) & 1u);   // round-to-nearest-even
  return (u16)(u >> 16);
}

// ---------------------------------------------------------------------------
// zero the small control block (stats + bucket totals)
__global__ void k_init(float* __restrict__ stats, u32* __restrict__ bucketTotal) {
  for (int i = threadIdx.x; i < 1024; i += blockDim.x) stats[i] = 0.f;
  for (int i = threadIdx.x; i < NBMAX + 1; i += blockDim.x) bucketTotal[i] = 0u;
}

// ---------------------------------------------------------------------------
// fused: global sum-of-squares of directions + per-bucket dst histogram
__global__ void k_norm_hist(const int* __restrict__ ei, const float* __restrict__ pos,
                            int E, int NB, float* __restrict__ stats,
                            u32* __restrict__ bucketTotal) {
  __shared__ u32 lh[NBMAX];
  __shared__ float red[16];
  for (int i = threadIdx.x; i < NB; i += blockDim.x) lh[i] = 0u;
  __syncthreads();
  int tid = blockIdx.x * blockDim.x + threadIdx.x;
  int stride = gridDim.x * blockDim.x;
  float acc = 0.f;
  for (int e = tid; e < E; e += stride) {
    int s = ei[e], d = ei[E + e];
    float d0 = pos[3 * s + 0] - pos[3 * d + 0];
    float d1 = pos[3 * s + 1] - pos[3 * d + 1];
    float d2 = pos[3 * s + 2] - pos[3 * d + 2];
    acc = fmaf(d0, d0, acc);
    acc = fmaf(d1, d1, acc);
    acc = fmaf(d2, d2, acc);
    atomicAdd(&lh[d >> NPB_SHIFT], 1u);
  }
#pragma unroll
  for (int off = 32; off > 0; off >>= 1) acc += __shfl_down(acc, off, 64);
  if ((threadIdx.x & 63) == 0) red[threadIdx.x >> 6] = acc;
  __syncthreads();
  if (threadIdx.x == 0) {
    float s = 0.f;
    for (int w = 0; w < (int)(blockDim.x >> 6); w++) s += red[w];
    atomicAdd(&stats[0], s);
  }
  for (int i = threadIdx.x; i < NB; i += blockDim.x)
    if (lh[i]) atomicAdd(&bucketTotal[i], lh[i]);
}

// ---------------------------------------------------------------------------
// exclusive scan of bucket totals — single wave, shfl prefix scan
__global__ void k_scan(const u32* __restrict__ bucketTotal, u32* __restrict__ base,
                       u32* __restrict__ cursor, int NB) {
  int lane = threadIdx.x;  // launched with 64 threads, 1 block
  u32 run = 0;
  for (int b0 = 0; b0 < NB; b0 += 64) {
    int b = b0 + lane;
    u32 v = (b < NB) ? bucketTotal[b] : 0u;
    u32 s = v;
#pragma unroll
    for (int off = 1; off < 64; off <<= 1) {
      u32 t = __shfl_up(s, off, 64);
      if (lane >= off) s += t;
    }
    u32 excl = run + s - v;
    if (b < NB) { base[b] = excl; cursor[b] = excl; }
    run += __shfl(s, 63, 64);   // broadcast chunk total
  }
  if (lane == 0) base[NB] = run;
}

// ---------------------------------------------------------------------------
// bin edges by dst bucket: sorted2[slot] = {src, dst} (coalesced-consumable
// by layer1) + ln8[slot] = dst & 63 (compact lane id for bucket_max).
__global__ void k_place(const int* __restrict__ ei, int E, int NB,
                        u32* __restrict__ cursor, uint2* __restrict__ sorted2,
                        u8* __restrict__ ln8) {
  __shared__ u32 lh[NBMAX];
  __shared__ u32 lbase[NBMAX];
  for (int i = threadIdx.x; i < NB; i += blockDim.x) lh[i] = 0u;
  __syncthreads();
  int tid = blockIdx.x * blockDim.x + threadIdx.x;
  int stride = gridDim.x * blockDim.x;
  for (int e = tid; e < E; e += stride) atomicAdd(&lh[ei[E + e] >> NPB_SHIFT], 1u);
  __syncthreads();
  for (int i = threadIdx.x; i < NB; i += blockDim.x) {
    u32 c = lh[i];
    lbase[i] = c ? atomicAdd(&cursor[i], c) : 0u;
    lh[i] = 0u;
  }
  __syncthreads();
  for (int e = tid; e < E; e += stride) {
    int s = ei[e];
    int d = ei[E + e];
    int b = d >> NPB_SHIFT;
    u32 slot = lbase[b] + atomicAdd(&lh[b], 1u);
    sorted2[slot] = make_uint2((u32)s, (u32)d);
    ln8[slot] = (u8)(d & (NPB - 1));
  }
}

// ---------------------------------------------------------------------------
// layer 1, two-phase, slot-ordered. Phase A: 256 parallel gathers -> LDS
// (sorted2 coalesced; pos/x L2-resident). Phase B RE-TILED: each thread owns
// 8 channels x 8 edges -> one uint4 (16B) store per edge-row segment; wave
// writes 1 KB contiguous. 8x fewer LDS reads (8 addrs x 8-lane broadcast)
// and 8x fewer store instructions than the 1-channel/thread version.
__global__ __launch_bounds__(256) void k_layer1(
    const int* __restrict__ ei, const float* __restrict__ pos,
    const float* __restrict__ x, const float* __restrict__ W1,
    const float* __restrict__ b1, u16* __restrict__ h,
    const float* __restrict__ stats, float* __restrict__ gsum,
    float* __restrict__ gsq, int E, const uint2* __restrict__ sorted2) {
  __shared__ float in6[6][256];
  __shared__ float ssum[64], ssq[64];
  float invn = 1.0f / sqrtf(stats[0]);
  int t = threadIdx.x;
  int lane = t & 63;
  int wv = t >> 6;         // wave 0..3: edges [wv*64, wv*64+64) of the chunk
  int eslot = lane >> 3;   // 0..7
  int c0 = (lane & 7) * 8; // this thread's 8 channels
  float w[6][8];
#pragma unroll
  for (int k = 0; k < 6; k++)
#pragma unroll
    for (int j = 0; j < 8; j++) w[k][j] = W1[k * 64 + c0 + j];
  float bias[8];
#pragma unroll
  for (int j = 0; j < 8; j++) bias[j] = b1[c0 + j];
  float psum[8] = {0.f, 0.f, 0.f, 0.f, 0.f, 0.f, 0.f, 0.f};
  float psq[8] = {0.f, 0.f, 0.f, 0.f, 0.f, 0.f, 0.f, 0.f};

  int chunks = (E + 255) >> 8;
  for (int c = blockIdx.x; c < chunks; c += gridDim.x) {
    long e0 = (long)c << 8;
    int e = (int)e0 + t;   // slot id (phase A: one edge per thread)
    float v[6] = {0.f, 0.f, 0.f, 0.f, 0.f, 0.f};
    if (e < E) {
      int s, d;
      if (sorted2) {
        uint2 sd = sorted2[e];
        s = (int)sd.x;
        d = (int)sd.y;
      } else {
        s = ei[e];
        d = ei[E + e];
      }
      float p0 = pos[3 * s + 0], p1 = pos[3 * s + 1], p2 = pos[3 * s + 2];
      float q0 = pos[3 * d + 0], q1 = pos[3 * d + 1], q2 = pos[3 * d + 2];
      v[0] = (p0 - q0) * invn;
      v[1] = (p1 - q1) * invn;
      v[2] = (p2 - q2) * invn;
      v[3] = x[3 * d + 0];
      v[4] = x[3 * d + 1];
      v[5] = x[3 * d + 2];
    }
    __syncthreads();  // previous chunk's phase-B reads done
#pragma unroll
    for (int k = 0; k < 6; k++) in6[k][t] = v[k];
    __syncthreads();
    int lim = E - (int)e0;
    if (lim > 256) lim = 256;
#pragma unroll
    for (int i = 0; i < 8; i++) {
      int el = wv * 64 + i * 8 + eslot;  // 8 consecutive rows per wave-iter
      if (el >= lim) continue;
      float hv[8];
#pragma unroll
      for (int j = 0; j < 8; j++) {
        float acc = bias[j];
#pragma unroll
        for (int k = 0; k < 6; k++) acc = fmaf(in6[k][el], w[k][j], acc);
        hv[j] = fmaxf(acc, 0.f);
      }
      u32 pk[4];
#pragma unroll
      for (int p = 0; p < 4; p++) {
        u16 lo = f2bf(hv[2 * p]);
        u16 hi = f2bf(hv[2 * p + 1]);
        pk[p] = (u32)lo | ((u32)hi << 16);
        float f0 = bf2f(lo), f1 = bf2f(hi);
        psum[2 * p] += f0;
        psq[2 * p] = fmaf(f0, f0, psq[2 * p]);
        psum[2 * p + 1] += f1;
        psq[2 * p + 1] = fmaf(f1, f1, psq[2 * p + 1]);
      }
      *(uint4*)(h + (e0 + el) * 64 + c0) = make_uint4(pk[0], pk[1], pk[2], pk[3]);
    }
  }
  if (t < 64) { ssum[t] = 0.f; ssq[t] = 0.f; }
  __syncthreads();
#pragma unroll
  for (int j = 0; j < 8; j++) {
    atomicAdd(&ssum[c0 + j], psum[j]);
    atomicAdd(&ssq[c0 + j], psq[j]);
  }
  __syncthreads();
  if (t < 64) {
    atomicAdd(&gsum[t], ssum[t]);
    atomicAdd(&gsq[t], ssq[t]);
  }
}

// ---------------------------------------------------------------------------
// layers 2/3: h = relu( bn_in(h) @ W + b ), in place. BN finalize computed in
// a 64-thread prologue from gsum/gsq, folded into W' = sc_in*W and
// bias' = b + sh_in^T W, so A-frags are RAW uint4 loads.
__global__ __launch_bounds__(256) void k_layer_mfma(
    u16* h, const float* __restrict__ W, const float* __restrict__ b,
    const float* __restrict__ gsum_in, const float* __restrict__ gsq_in,
    const float* __restrict__ g_in, const float* __restrict__ be_in, float invE,
    float* __restrict__ gsum, float* __restrict__ gsq, int E) {
  __shared__ float sc_s[64], sh_s[64];
  if (threadIdx.x < 64) {
    int c = threadIdx.x;
    float mu = gsum_in[c] * invE;
    float var = gsq_in[c] * invE - mu * mu;
    float s = g_in[c] * rsqrtf(var + BN_EPS);
    sc_s[c] = s;
    sh_s[c] = be_in[c] - mu * s;
  }
  __syncthreads();

  int lane = threadIdx.x & 63;
  int m = lane & 15;
  int q = lane >> 4;

  short8 bf[4][2];
  float bias[4];
#pragma unroll
  for (int t = 0; t < 4; t++) {
    int n = t * 16 + m;
    float bb = b[n];
    for (int k = 0; k < 64; k++) bb = fmaf(sh_s[k], W[k * 64 + n], bb);
    bias[t] = bb;
#pragma unroll
    for (int s = 0; s < 2; s++)
#pragma unroll
      for (int j = 0; j < 8; j++) {
        int k = s * 32 + q * 8 + j;
        bf[t][s][j] = (short)f2bf(W[k * 64 + n] * sc_s[k]);
      }
  }

  float psum[4] = {0.f, 0.f, 0.f, 0.f}, psq[4] = {0.f, 0.f, 0.f, 0.f};

  int tiles = E >> 4;
  int gw = ((int)blockIdx.x * (blockDim.x >> 6)) + (threadIdx.x >> 6);
  int nw = (int)gridDim.x * (blockDim.x >> 6);

  for (int tile = gw; tile < tiles; tile += nw) {
    long e0 = (long)tile * 16;
    const u16* rowp = h + (e0 + m) * 64 + q * 8;
    short8 a0 = *(const short8*)(rowp);
    short8 a1 = *(const short8*)(rowp + 32);
    floatx4 acc[4];
#pragma unroll
    for (int t = 0; t < 4; t++) acc[t] = (floatx4){0.f, 0.f, 0.f, 0.f};
#pragma unroll
    for (int t = 0; t < 4; t++)
      acc[t] = __builtin_amdgcn_mfma_f32_16x16x32_bf16(a0, bf[t][0], acc[t], 0, 0, 0);
#pragma unroll
    for (int t = 0; t < 4; t++)
      acc[t] = __builtin_amdgcn_mfma_f32_16x16x32_bf16(a1, bf[t][1], acc[t], 0, 0, 0);

#pragma unroll
    for (int t = 0; t < 4; t++) {
#pragma unroll
      for (int r = 0; r < 4; r++) {
        float v = acc[t][r] + bias[t];
        v = fmaxf(v, 0.f);
        u16 hb = f2bf(v);
        h[(e0 + q * 4 + r) * 64 + t * 16 + m] = hb;
        float hf = bf2f(hb);
        psum[t] += hf;
        psq[t] = fmaf(hf, hf, psq[t]);
      }
    }
  }

#pragma unroll
  for (int t = 0; t < 4; t++) {
    psum[t] += __shfl_xor(psum[t], 16, 64);
    psum[t] += __shfl_xor(psum[t], 32, 64);
    psq[t] += __shfl_xor(psq[t], 16, 64);
    psq[t] += __shfl_xor(psq[t], 32, 64);
  }
  __shared__ float ssum[64], ssq[64];
  if (threadIdx.x < 64) { ssum[threadIdx.x] = 0.f; ssq[threadIdx.x] = 0.f; }
  __syncthreads();
  if (q == 0) {
#pragma unroll
    for (int t = 0; t < 4; t++) {
      atomicAdd(&ssum[t * 16 + m], psum[t]);
      atomicAdd(&ssq[t * 16 + m], psq[t]);
    }
  }
  __syncthreads();
  if (threadIdx.x < 64) {
    atomicAdd(&gsum[threadIdx.x], ssum[threadIdx.x]);
    atomicAdd(&gsq[threadIdx.x], ssq[threadIdx.x]);
  }
}

// ---------------------------------------------------------------------------
// per-bucket scatter-max in LDS, STREAMING: h is in sorted-slot order, so
// each block reads a contiguous [base[b],base[b+1]) range of h (coalesced
// 1 KB/wave-load) plus 1 byte/edge of lane ids. Max on raw bf16 bit-patterns
// (relu out >= 0 -> unsigned-ordered; per-channel XOR mask handles gamma<0),
// bit16 = non-empty marker. BN3 applied once per node-channel in epilogue.
__global__ __launch_bounds__(256) void k_bucket_max(
    const u8* __restrict__ ln8, const u32* __restrict__ base,
    const u16* __restrict__ h, const float* __restrict__ gsum3,
    const float* __restrict__ gsq3, const float* __restrict__ g3,
    const float* __restrict__ be3, float invE, float* __restrict__ outf, int N) {
  __shared__ u32 tile[NPB * 64];  // 16 KB of keys; 0 == empty
  for (int i = threadIdx.x; i < NPB * 64; i += blockDim.x) tile[i] = 0u;
  int b = blockIdx.x;
  u32 start = base[b];
  int cnt = (int)(base[b + 1] - start);
  int t = threadIdx.x;
  int es = t >> 3;       // edge slot 0..31
  int c0 = (t & 7) * 8;  // this thread's 8 channels
  u32 mm[4];             // per-channel-pair xor masks (0xFFFF where gamma<0)
#pragma unroll
  for (int p = 0; p < 4; p++) {
    u32 m0 = (g3[c0 + 2 * p] < 0.f) ? 0xFFFFu : 0u;
    u32 m1 = (g3[c0 + 2 * p + 1] < 0.f) ? 0xFFFFu : 0u;
    mm[p] = m0 | (m1 << 16);
  }
  __syncthreads();

  for (int i0 = 0; i0 < cnt; i0 += 128) {  // 32 edges x 4-deep unroll
    uint4 raw[4];
    u32 ln[4];
    int ok[4];
#pragma unroll
    for (int u_ = 0; u_ < 4; u_++) {
      int sl = i0 + u_ * 32 + es;
      ok[u_] = sl < cnt;
      if (ok[u_]) {
        ln[u_] = (u32)ln8[start + sl];
        raw[u_] = *(const uint4*)(h + (long)(start + sl) * 64 + c0);
      }
    }
#pragma unroll
    for (int u_ = 0; u_ < 4; u_++) {
      if (!ok[u_]) continue;
      unsigned w[4] = {raw[u_].x, raw[u_].y, raw[u_].z, raw[u_].w};
      u32 key[8];
#pragma unroll
      for (int p = 0; p < 4; p++) {
        u32 wx = w[p] ^ mm[p];
        key[2 * p] = (wx & 0xFFFFu) | 0x10000u;
        key[2 * p + 1] = (wx >> 16) | 0x10000u;
      }
      u32 baseA = ln[u_] * 64u + (u32)c0;
      // per-edge-slot rotated channel order -> 2 lanes/bank (min for wave64)
#pragma unroll
      for (int jj = 0; jj < 8; jj++) {
        int j = (jj + es) & 7;
        atomicMax(&tile[baseA + j], key[j]);
      }
    }
  }
  __syncthreads();
  // epilogue: stride-256 means channel c = t&63 is fixed per thread
  int c = t & 63;
  float mu = gsum3[c] * invE;
  float var = gsq3[c] * invE - mu * mu;
  float sc = g3[c] * rsqrtf(var + BN_EPS);
  float sh = be3[c] - mu * sc;
  u32 me = (g3[c] < 0.f) ? 0xFFFFu : 0u;
  int node0 = b * NPB;
  for (int l = t; l < NPB * 64; l += blockDim.x) {
    int node = node0 + (l >> 6);
    if (node < N) {
      u32 k = tile[l];
      float v = (k == 0u) ? 0.f : fmaf(bf2f((u16)((k & 0xFFFFu) ^ me)), sc, sh);
      outf[(long)node * 64 + (l & 63)] = v;
    }
  }
}

// ---------------------------------------------------------------------------
// fallback path kernels (only if ws too small): -inf init, atomic scatter, fixup
__global__ void k_initout(float* __restrict__ outf, long n, float* __restrict__ stats,
                          u32* __restrict__ bucketTotal) {
  long i = (long)blockIdx.x * blockDim.x + threadIdx.x;
  long stride = (long)gridDim.x * blockDim.x;
  for (long j = i; j < n; j += stride) outf[j] = __uint_as_float(0xFF800000u);
  if (i < 1024) stats[i] = 0.f;
  if (i < NBMAX + 1) bucketTotal[i] = 0u;
}
__global__ void k_scatter(const int* __restrict__ ei, const u16* __restrict__ h,
                          const float* __restrict__ gsum3, const float* __restrict__ gsq3,
                          const float* __restrict__ g3, const float* __restrict__ be3,
                          float invE, float* outf, int E) {
  int lane = threadIdx.x & 63;
  int gw = ((int)blockIdx.x * (blockDim.x >> 6)) + (threadIdx.x >> 6);
  int nw = (int)gridDim.x * (blockDim.x >> 6);
  float mu = gsum3[lane] * invE;
  float var = gsq3[lane] * invE - mu * mu;
  float sc = g3[lane] * rsqrtf(var + BN_EPS);
  float sh = be3[lane] - mu * sc;
  for (int e = gw; e < E; e += nw) {
    int d = ei[E + e];
    float v = fmaf(bf2f(h[(long)e * 64 + lane]), sc, sh);
    float* addr = outf + (long)d * 64 + lane;
    if (v >= 0.f)
      atomicMax((int*)addr, __float_as_int(v));
    else
      atomicMin((unsigned int*)addr, __float_as_uint(v));
  }
}
__global__ void k_out(float* __restrict__ outf, long n) {
  long i = (long)blockIdx.x * blockDim.x + threadIdx.x;
  long stride = (long)gridDim.x * blockDim.x;
  for (long j = i; j < n; j += stride) {
    float v = outf[j];
    unsigned u = __float_as_uint(v);
    if ((u & 0x7F800000u) == 0x7F800000u) v = 0.f;
    outf[j] = v;
  }
}

// ---------------------------------------------------------------------------
extern "C" void kernel_launch(void* const* d_in, const int* in_sizes, int n_in,
                              void* d_out, int out_size, void* d_ws, size_t ws_size,
                              hipStream_t stream) {
  const float* x = (const float*)d_in[0];
  const float* pos = (const float*)d_in[1];
  const int* ei = (const int*)d_in[2];
  const float* W1 = (const float*)d_in[3];
  const float* b1 = (const float*)d_in[4];
  const float* g1 = (const float*)d_in[5];
  const float* be1 = (const float*)d_in[6];
  const float* W2 = (const float*)d_in[7];
  const float* b2 = (const float*)d_in[8];
  const float* g2 = (const float*)d_in[9];
  const float* be2 = (const float*)d_in[10];
  const float* W3 = (const float*)d_in[11];
  const float* b3 = (const float*)d_in[12];
  const float* g3 = (const float*)d_in[13];
  const float* be3 = (const float*)d_in[14];

  int N = in_sizes[0] / 3;
  int E = in_sizes[2] / 2;
  int NB = (N + NPB - 1) / NPB;
  long n_out = (long)N * 64;

  char* wsb = (char*)d_ws;
  u16* h = (u16*)wsb;  // [E,64] bf16 activations, in sorted-slot order
  size_t off = (size_t)E * 64 * 2;
  float* stats = (float*)(wsb + off);
  off += 1024 * 4;
  u32* bucketTotal = (u32*)(wsb + off);
  off += (NBMAX + 1) * 4;
  u32* baseArr = (u32*)(wsb + off);
  off += (NBMAX + 1) * 4;
  u32* cursor = (u32*)(wsb + off);
  off += NBMAX * 4;
  off = (off + 7) & ~(size_t)7;  // 8-align for uint2
  uint2* sorted2 = (uint2*)(wsb + off);
  off += (size_t)E * 8;
  u8* ln8 = (u8*)(wsb + off);
  off += (size_t)E;
  size_t need = off;

  float* gsum1 = stats + 64, * gsq1 = stats + 128;
  float* gsum2 = stats + 192, * gsq2 = stats + 256;
  float* gsum3 = stats + 320, * gsq3 = stats + 384;

  float* outf = (float*)d_out;
  float invE = 1.0f / (float)E;
  bool binned = (ws_size >= need) && (NB <= NBMAX);

  if (binned) {
    k_init<<<1, 1024, 0, stream>>>(stats, bucketTotal);
    k_norm_hist<<<512, 256, 0, stream>>>(ei, pos, E, NB, stats, bucketTotal);
    k_scan<<<1, 64, 0, stream>>>(bucketTotal, baseArr, cursor, NB);
    k_place<<<512, 256, 0, stream>>>(ei, E, NB, cursor, sorted2, ln8);
    k_layer1<<<2048, 256, 0, stream>>>(ei, pos, x, W1, b1, h, stats, gsum1, gsq1, E, sorted2);
    k_layer_mfma<<<1536, 256, 0, stream>>>(h, W2, b2, gsum1, gsq1, g1, be1, invE, gsum2, gsq2, E);
    k_layer_mfma<<<1536, 256, 0, stream>>>(h, W3, b3, gsum2, gsq2, g2, be2, invE, gsum3, gsq3, E);
    k_bucket_max<<<NB, 256, 0, stream>>>(ln8, baseArr, h, gsum3, gsq3, g3, be3, invE, outf, N);
  } else {
    k_initout<<<4096, 256, 0, stream>>>(outf, n_out, stats, bucketTotal);
    k_norm_hist<<<512, 256, 0, stream>>>(ei, pos, E, NB <= NBMAX ? NB : 1, stats, bucketTotal);
    k_layer1<<<2048, 256, 0, stream>>>(ei, pos, x, W1, b1, h, stats, gsum1, gsq1, E, (const uint2*)nullptr);
    k_layer_mfma<<<1536, 256, 0, stream>>>(h, W2, b2, gsum1, gsq1, g1, be1, invE, gsum2, gsq2, E);
    k_layer_mfma<<<1536, 256, 0, stream>>>(h, W3, b3, gsum2, gsq2, g2, be2, invE, gsum3, gsq3, E);
    k_scatter<<<2048, 256, 0, stream>>>(ei, h, gsum3, gsq3, g3, be3, invE, outf, E);
    k_out<<<2048, 256, 0, stream>>>(outf, n_out);
  }
}

// Round 8
// 482.765 us; speedup vs baseline: 1.1822x; 1.0838x over previous
//
#include <hip/hip_runtime.h>
#include <stdint.h>

typedef unsigned char u8;
typedef unsigned short u16;
typedef unsigned int u32;
typedef __attribute__((ext_vector_type(8))) short short8;
typedef __attribute__((ext_vector_type(4))) float floatx4;

#define BN_EPS 1e-5f
#define NPB 64        // nodes per bucket (power of 2; bucket = dst >> NPB_SHIFT)
#define NPB_SHIFT 6
#define NBMAX 2048

__device__ __forceinline__ float bf2f(u16 u) { return __uint_as_float(((unsigned)u) << 16); }
__device__ __forceinline__ u16 f2bf(float f) {
  unsigned u = __float_as_uint(f);
  u += 0x7FFFu + ((u >> 16) & 1u);   // round-to-nearest-even
  return (u16)(u >> 16);
}

// ---------------------------------------------------------------------------
// zero the small control block (stats + bucket totals)
__global__ void k_init(float* __restrict__ stats, u32* __restrict__ bucketTotal) {
  for (int i = threadIdx.x; i < 1024; i += blockDim.x) stats[i] = 0.f;
  for (int i = threadIdx.x; i < NBMAX + 1; i += blockDim.x) bucketTotal[i] = 0u;
}

// ---------------------------------------------------------------------------
// fused: global sum-of-squares of directions + per-bucket dst histogram
__global__ void k_norm_hist(const int* __restrict__ ei, const float* __restrict__ pos,
                            int E, int NB, float* __restrict__ stats,
                            u32* __restrict__ bucketTotal) {
  __shared__ u32 lh[NBMAX];
  __shared__ float red[16];
  for (int i = threadIdx.x; i < NB; i += blockDim.x) lh[i] = 0u;
  __syncthreads();
  int tid = blockIdx.x * blockDim.x + threadIdx.x;
  int stride = gridDim.x * blockDim.x;
  float acc = 0.f;
  for (int e = tid; e < E; e += stride) {
    int s = ei[e], d = ei[E + e];
    float d0 = pos[3 * s + 0] - pos[3 * d + 0];
    float d1 = pos[3 * s + 1] - pos[3 * d + 1];
    float d2 = pos[3 * s + 2] - pos[3 * d + 2];
    acc = fmaf(d0, d0, acc);
    acc = fmaf(d1, d1, acc);
    acc = fmaf(d2, d2, acc);
    atomicAdd(&lh[d >> NPB_SHIFT], 1u);
  }
#pragma unroll
  for (int off = 32; off > 0; off >>= 1) acc += __shfl_down(acc, off, 64);
  if ((threadIdx.x & 63) == 0) red[threadIdx.x >> 6] = acc;
  __syncthreads();
  if (threadIdx.x == 0) {
    float s = 0.f;
    for (int w = 0; w < (int)(blockDim.x >> 6); w++) s += red[w];
    atomicAdd(&stats[0], s);
  }
  for (int i = threadIdx.x; i < NB; i += blockDim.x)
    if (lh[i]) atomicAdd(&bucketTotal[i], lh[i]);
}

// ---------------------------------------------------------------------------
// exclusive scan of bucket totals — single wave, shfl prefix scan
__global__ void k_scan(const u32* __restrict__ bucketTotal, u32* __restrict__ base,
                       u32* __restrict__ cursor, int NB) {
  int lane = threadIdx.x;  // launched with 64 threads, 1 block
  u32 run = 0;
  for (int b0 = 0; b0 < NB; b0 += 64) {
    int b = b0 + lane;
    u32 v = (b < NB) ? bucketTotal[b] : 0u;
    u32 s = v;
#pragma unroll
    for (int off = 1; off < 64; off <<= 1) {
      u32 t = __shfl_up(s, off, 64);
      if (lane >= off) s += t;
    }
    u32 excl = run + s - v;
    if (b < NB) { base[b] = excl; cursor[b] = excl; }
    run += __shfl(s, 63, 64);   // broadcast chunk total
  }
  if (lane == 0) base[NB] = run;
}

// ---------------------------------------------------------------------------
// bin edges by dst bucket: sorted2[slot] = {src, dst} (coalesced-consumable
// by layer1) + ln8[slot] = dst & 63 (compact lane id for bucket_max).
__global__ void k_place(const int* __restrict__ ei, int E, int NB,
                        u32* __restrict__ cursor, uint2* __restrict__ sorted2,
                        u8* __restrict__ ln8) {
  __shared__ u32 lh[NBMAX];
  __shared__ u32 lbase[NBMAX];
  for (int i = threadIdx.x; i < NB; i += blockDim.x) lh[i] = 0u;
  __syncthreads();
  int tid = blockIdx.x * blockDim.x + threadIdx.x;
  int stride = gridDim.x * blockDim.x;
  for (int e = tid; e < E; e += stride) atomicAdd(&lh[ei[E + e] >> NPB_SHIFT], 1u);
  __syncthreads();
  for (int i = threadIdx.x; i < NB; i += blockDim.x) {
    u32 c = lh[i];
    lbase[i] = c ? atomicAdd(&cursor[i], c) : 0u;
    lh[i] = 0u;
  }
  __syncthreads();
  for (int e = tid; e < E; e += stride) {
    int s = ei[e];
    int d = ei[E + e];
    int b = d >> NPB_SHIFT;
    u32 slot = lbase[b] + atomicAdd(&lh[b], 1u);
    sorted2[slot] = make_uint2((u32)s, (u32)d);
    ln8[slot] = (u8)(d & (NPB - 1));
  }
}

// ---------------------------------------------------------------------------
// layer 1, two-phase, slot-ordered. Phase A: 256 parallel gathers -> LDS
// (sorted2 coalesced; pos/x L2-resident). Phase B: each thread owns 8
// channels x 8 edges -> one uint4 (16B) store per edge segment; wave writes
// 1 KB contiguous; 8x fewer LDS reads and store instructions.
__global__ __launch_bounds__(256) void k_layer1(
    const int* __restrict__ ei, const float* __restrict__ pos,
    const float* __restrict__ x, const float* __restrict__ W1,
    const float* __restrict__ b1, u16* __restrict__ h,
    const float* __restrict__ stats, float* __restrict__ gsum,
    float* __restrict__ gsq, int E, const uint2* __restrict__ sorted2) {
  __shared__ float in6[6][256];
  __shared__ float ssum[64], ssq[64];
  float invn = 1.0f / sqrtf(stats[0]);
  int t = threadIdx.x;
  int lane = t & 63;
  int wv = t >> 6;         // wave 0..3: edges [wv*64, wv*64+64) of the chunk
  int eslot = lane >> 3;   // 0..7
  int c0 = (lane & 7) * 8; // this thread's 8 channels
  float w[6][8];
#pragma unroll
  for (int k = 0; k < 6; k++)
#pragma unroll
    for (int j = 0; j < 8; j++) w[k][j] = W1[k * 64 + c0 + j];
  float bias[8];
#pragma unroll
  for (int j = 0; j < 8; j++) bias[j] = b1[c0 + j];
  float psum[8] = {0.f, 0.f, 0.f, 0.f, 0.f, 0.f, 0.f, 0.f};
  float psq[8] = {0.f, 0.f, 0.f, 0.f, 0.f, 0.f, 0.f, 0.f};

  int chunks = (E + 255) >> 8;
  for (int c = blockIdx.x; c < chunks; c += gridDim.x) {
    long e0 = (long)c << 8;
    int e = (int)e0 + t;   // slot id (phase A: one edge per thread)
    float v[6] = {0.f, 0.f, 0.f, 0.f, 0.f, 0.f};
    if (e < E) {
      int s, d;
      if (sorted2) {
        uint2 sd = sorted2[e];
        s = (int)sd.x;
        d = (int)sd.y;
      } else {
        s = ei[e];
        d = ei[E + e];
      }
      float p0 = pos[3 * s + 0], p1 = pos[3 * s + 1], p2 = pos[3 * s + 2];
      float q0 = pos[3 * d + 0], q1 = pos[3 * d + 1], q2 = pos[3 * d + 2];
      v[0] = (p0 - q0) * invn;
      v[1] = (p1 - q1) * invn;
      v[2] = (p2 - q2) * invn;
      v[3] = x[3 * d + 0];
      v[4] = x[3 * d + 1];
      v[5] = x[3 * d + 2];
    }
    __syncthreads();  // previous chunk's phase-B reads done
#pragma unroll
    for (int k = 0; k < 6; k++) in6[k][t] = v[k];
    __syncthreads();
    int lim = E - (int)e0;
    if (lim > 256) lim = 256;
#pragma unroll
    for (int i = 0; i < 8; i++) {
      int el = wv * 64 + i * 8 + eslot;  // 8 consecutive rows per wave-iter
      if (el >= lim) continue;
      float hv[8];
#pragma unroll
      for (int j = 0; j < 8; j++) {
        float acc = bias[j];
#pragma unroll
        for (int k = 0; k < 6; k++) acc = fmaf(in6[k][el], w[k][j], acc);
        hv[j] = fmaxf(acc, 0.f);
      }
      u32 pk[4];
#pragma unroll
      for (int p = 0; p < 4; p++) {
        u16 lo = f2bf(hv[2 * p]);
        u16 hi = f2bf(hv[2 * p + 1]);
        pk[p] = (u32)lo | ((u32)hi << 16);
        float f0 = bf2f(lo), f1 = bf2f(hi);
        psum[2 * p] += f0;
        psq[2 * p] = fmaf(f0, f0, psq[2 * p]);
        psum[2 * p + 1] += f1;
        psq[2 * p + 1] = fmaf(f1, f1, psq[2 * p + 1]);
      }
      *(uint4*)(h + (e0 + el) * 64 + c0) = make_uint4(pk[0], pk[1], pk[2], pk[3]);
    }
  }
  if (t < 64) { ssum[t] = 0.f; ssq[t] = 0.f; }
  __syncthreads();
#pragma unroll
  for (int j = 0; j < 8; j++) {
    atomicAdd(&ssum[c0 + j], psum[j]);
    atomicAdd(&ssq[c0 + j], psq[j]);
  }
  __syncthreads();
  if (t < 64) {
    atomicAdd(&gsum[t], ssum[t]);
    atomicAdd(&gsq[t], ssq[t]);
  }
}

// ---------------------------------------------------------------------------
// layers 2/3: h = relu( bn_in(h) @ W + b ), in place, OPERAND-SWAPPED MFMA:
// mfma(W-frag, h-frag) transposes C so each thread holds 4 CONSECUTIVE
// channels of ONE edge -> one 8B packed store per t (4 stores/tile instead
// of 16x2B). Fragments and loads identical to before; BN fold unchanged.
__global__ __launch_bounds__(256) void k_layer_mfma(
    u16* h, const float* __restrict__ W, const float* __restrict__ b,
    const float* __restrict__ gsum_in, const float* __restrict__ gsq_in,
    const float* __restrict__ g_in, const float* __restrict__ be_in, float invE,
    float* __restrict__ gsum, float* __restrict__ gsq, int E) {
  __shared__ float sc_s[64], sh_s[64], biasf[64];
  if (threadIdx.x < 64) {
    int c = threadIdx.x;
    float mu = gsum_in[c] * invE;
    float var = gsq_in[c] * invE - mu * mu;
    float s = g_in[c] * rsqrtf(var + BN_EPS);
    sc_s[c] = s;
    sh_s[c] = be_in[c] - mu * s;
  }
  __syncthreads();
  if (threadIdx.x < 64) {  // folded bias' = b + sh_in^T W, once per channel
    int c = threadIdx.x;
    float bb = b[c];
    for (int k = 0; k < 64; k++) bb = fmaf(sh_s[k], W[k * 64 + c], bb);
    biasf[c] = bb;
  }
  __syncthreads();

  int lane = threadIdx.x & 63;
  int m = lane & 15;
  int q = lane >> 4;

  short8 bf[4][2];
  float bias_sw[4][4];
#pragma unroll
  for (int t = 0; t < 4; t++) {
    int n = t * 16 + m;
#pragma unroll
    for (int s = 0; s < 2; s++)
#pragma unroll
      for (int j = 0; j < 8; j++) {
        int k = s * 32 + q * 8 + j;
        bf[t][s][j] = (short)f2bf(W[k * 64 + n] * sc_s[k]);
      }
#pragma unroll
    for (int r = 0; r < 4; r++) bias_sw[t][r] = biasf[t * 16 + q * 4 + r];
  }

  float psum[4][4], psq[4][4];
#pragma unroll
  for (int t = 0; t < 4; t++)
#pragma unroll
    for (int r = 0; r < 4; r++) { psum[t][r] = 0.f; psq[t][r] = 0.f; }

  int tiles = E >> 4;
  int gw = ((int)blockIdx.x * (blockDim.x >> 6)) + (threadIdx.x >> 6);
  int nw = (int)gridDim.x * (blockDim.x >> 6);

  for (int tile = gw; tile < tiles; tile += nw) {
    long e0 = (long)tile * 16;
    const u16* rowp = h + (e0 + m) * 64 + q * 8;
    short8 a0 = *(const short8*)(rowp);
    short8 a1 = *(const short8*)(rowp + 32);
    floatx4 acc[4];
#pragma unroll
    for (int t = 0; t < 4; t++) acc[t] = (floatx4){0.f, 0.f, 0.f, 0.f};
    // swapped: W-frag as A, h-frag as B -> C[ch][edge]
#pragma unroll
    for (int t = 0; t < 4; t++)
      acc[t] = __builtin_amdgcn_mfma_f32_16x16x32_bf16(bf[t][0], a0, acc[t], 0, 0, 0);
#pragma unroll
    for (int t = 0; t < 4; t++)
      acc[t] = __builtin_amdgcn_mfma_f32_16x16x32_bf16(bf[t][1], a1, acc[t], 0, 0, 0);

    u16* orow = h + (e0 + m) * 64;  // this thread's edge row
#pragma unroll
    for (int t = 0; t < 4; t++) {
      u16 xx[4];
#pragma unroll
      for (int r = 0; r < 4; r++) {
        float v = acc[t][r] + bias_sw[t][r];
        v = fmaxf(v, 0.f);
        u16 hb = f2bf(v);
        xx[r] = hb;
        float hf = bf2f(hb);
        psum[t][r] += hf;
        psq[t][r] = fmaf(hf, hf, psq[t][r]);
      }
      u32 p0 = (u32)xx[0] | ((u32)xx[1] << 16);
      u32 p1 = (u32)xx[2] | ((u32)xx[3] << 16);
      *(uint2*)(orow + t * 16 + q * 4) = make_uint2(p0, p1);
    }
  }

  // stats: channel t*16+q*4+r is fixed per thread; reduce across m-lanes
#pragma unroll
  for (int t = 0; t < 4; t++)
#pragma unroll
    for (int r = 0; r < 4; r++) {
#pragma unroll
      for (int off = 1; off < 16; off <<= 1) {
        psum[t][r] += __shfl_xor(psum[t][r], off, 64);
        psq[t][r] += __shfl_xor(psq[t][r], off, 64);
      }
    }
  __shared__ float ssum[64], ssq[64];
  if (threadIdx.x < 64) { ssum[threadIdx.x] = 0.f; ssq[threadIdx.x] = 0.f; }
  __syncthreads();
  if (m == 0) {
#pragma unroll
    for (int t = 0; t < 4; t++)
#pragma unroll
      for (int r = 0; r < 4; r++) {
        atomicAdd(&ssum[t * 16 + q * 4 + r], psum[t][r]);
        atomicAdd(&ssq[t * 16 + q * 4 + r], psq[t][r]);
      }
  }
  __syncthreads();
  if (threadIdx.x < 64) {
    atomicAdd(&gsum[threadIdx.x], ssum[threadIdx.x]);
    atomicAdd(&gsq[threadIdx.x], ssq[threadIdx.x]);
  }
}

// ---------------------------------------------------------------------------
// per-bucket scatter-max in LDS, STREAMING: h is in sorted-slot order, so
// each block reads a contiguous [base[b],base[b+1]) range of h (coalesced
// 1 KB/wave-load) plus 1 byte/edge of lane ids. Max on raw bf16 bit-patterns
// (relu out >= 0 -> unsigned-ordered; per-channel XOR mask handles gamma<0),
// bit16 = non-empty marker. BN3 applied once per node-channel in epilogue.
__global__ __launch_bounds__(256) void k_bucket_max(
    const u8* __restrict__ ln8, const u32* __restrict__ base,
    const u16* __restrict__ h, const float* __restrict__ gsum3,
    const float* __restrict__ gsq3, const float* __restrict__ g3,
    const float* __restrict__ be3, float invE, float* __restrict__ outf, int N) {
  __shared__ u32 tile[NPB * 64];  // 16 KB of keys; 0 == empty
  for (int i = threadIdx.x; i < NPB * 64; i += blockDim.x) tile[i] = 0u;
  int b = blockIdx.x;
  u32 start = base[b];
  int cnt = (int)(base[b + 1] - start);
  int t = threadIdx.x;
  int es = t >> 3;       // edge slot 0..31
  int c0 = (t & 7) * 8;  // this thread's 8 channels
  u32 mm[4];             // per-channel-pair xor masks (0xFFFF where gamma<0)
#pragma unroll
  for (int p = 0; p < 4; p++) {
    u32 m0 = (g3[c0 + 2 * p] < 0.f) ? 0xFFFFu : 0u;
    u32 m1 = (g3[c0 + 2 * p + 1] < 0.f) ? 0xFFFFu : 0u;
    mm[p] = m0 | (m1 << 16);
  }
  __syncthreads();

  for (int i0 = 0; i0 < cnt; i0 += 128) {  // 32 edges x 4-deep unroll
    uint4 raw[4];
    u32 ln[4];
    int ok[4];
#pragma unroll
    for (int u_ = 0; u_ < 4; u_++) {
      int sl = i0 + u_ * 32 + es;
      ok[u_] = sl < cnt;
      if (ok[u_]) {
        ln[u_] = (u32)ln8[start + sl];
        raw[u_] = *(const uint4*)(h + (long)(start + sl) * 64 + c0);
      }
    }
#pragma unroll
    for (int u_ = 0; u_ < 4; u_++) {
      if (!ok[u_]) continue;
      unsigned w[4] = {raw[u_].x, raw[u_].y, raw[u_].z, raw[u_].w};
      u32 key[8];
#pragma unroll
      for (int p = 0; p < 4; p++) {
        u32 wx = w[p] ^ mm[p];
        key[2 * p] = (wx & 0xFFFFu) | 0x10000u;
        key[2 * p + 1] = (wx >> 16) | 0x10000u;
      }
      u32 baseA = ln[u_] * 64u + (u32)c0;
      // per-edge-slot rotated channel order -> 2 lanes/bank (min for wave64)
#pragma unroll
      for (int jj = 0; jj < 8; jj++) {
        int j = (jj + es) & 7;
        atomicMax(&tile[baseA + j], key[j]);
      }
    }
  }
  __syncthreads();
  // epilogue: stride-256 means channel c = t&63 is fixed per thread
  int c = t & 63;
  float mu = gsum3[c] * invE;
  float var = gsq3[c] * invE - mu * mu;
  float sc = g3[c] * rsqrtf(var + BN_EPS);
  float sh = be3[c] - mu * sc;
  u32 me = (g3[c] < 0.f) ? 0xFFFFu : 0u;
  int node0 = b * NPB;
  for (int l = t; l < NPB * 64; l += blockDim.x) {
    int node = node0 + (l >> 6);
    if (node < N) {
      u32 k = tile[l];
      float v = (k == 0u) ? 0.f : fmaf(bf2f((u16)((k & 0xFFFFu) ^ me)), sc, sh);
      outf[(long)node * 64 + (l & 63)] = v;
    }
  }
}

// ---------------------------------------------------------------------------
// fallback path kernels (only if ws too small): -inf init, atomic scatter, fixup
__global__ void k_initout(float* __restrict__ outf, long n, float* __restrict__ stats,
                          u32* __restrict__ bucketTotal) {
  long i = (long)blockIdx.x * blockDim.x + threadIdx.x;
  long stride = (long)gridDim.x * blockDim.x;
  for (long j = i; j < n; j += stride) outf[j] = __uint_as_float(0xFF800000u);
  if (i < 1024) stats[i] = 0.f;
  if (i < NBMAX + 1) bucketTotal[i] = 0u;
}
__global__ void k_scatter(const int* __restrict__ ei, const u16* __restrict__ h,
                          const float* __restrict__ gsum3, const float* __restrict__ gsq3,
                          const float* __restrict__ g3, const float* __restrict__ be3,
                          float invE, float* outf, int E) {
  int lane = threadIdx.x & 63;
  int gw = ((int)blockIdx.x * (blockDim.x >> 6)) + (threadIdx.x >> 6);
  int nw = (int)gridDim.x * (blockDim.x >> 6);
  float mu = gsum3[lane] * invE;
  float var = gsq3[lane] * invE - mu * mu;
  float sc = g3[lane] * rsqrtf(var + BN_EPS);
  float sh = be3[lane] - mu * sc;
  for (int e = gw; e < E; e += nw) {
    int d = ei[E + e];
    float v = fmaf(bf2f(h[(long)e * 64 + lane]), sc, sh);
    float* addr = outf + (long)d * 64 + lane;
    if (v >= 0.f)
      atomicMax((int*)addr, __float_as_int(v));
    else
      atomicMin((unsigned int*)addr, __float_as_uint(v));
  }
}
__global__ void k_out(float* __restrict__ outf, long n) {
  long i = (long)blockIdx.x * blockDim.x + threadIdx.x;
  long stride = (long)gridDim.x * blockDim.x;
  for (long j = i; j < n; j += stride) {
    float v = outf[j];
    unsigned u = __float_as_uint(v);
    if ((u & 0x7F800000u) == 0x7F800000u) v = 0.f;
    outf[j] = v;
  }
}

// ---------------------------------------------------------------------------
extern "C" void kernel_launch(void* const* d_in, const int* in_sizes, int n_in,
                              void* d_out, int out_size, void* d_ws, size_t ws_size,
                              hipStream_t stream) {
  const float* x = (const float*)d_in[0];
  const float* pos = (const float*)d_in[1];
  const int* ei = (const int*)d_in[2];
  const float* W1 = (const float*)d_in[3];
  const float* b1 = (const float*)d_in[4];
  const float* g1 = (const float*)d_in[5];
  const float* be1 = (const float*)d_in[6];
  const float* W2 = (const float*)d_in[7];
  const float* b2 = (const float*)d_in[8];
  const float* g2 = (const float*)d_in[9];
  const float* be2 = (const float*)d_in[10];
  const float* W3 = (const float*)d_in[11];
  const float* b3 = (const float*)d_in[12];
  const float* g3 = (const float*)d_in[13];
  const float* be3 = (const float*)d_in[14];

  int N = in_sizes[0] / 3;
  int E = in_sizes[2] / 2;
  int NB = (N + NPB - 1) / NPB;
  long n_out = (long)N * 64;

  char* wsb = (char*)d_ws;
  u16* h = (u16*)wsb;  // [E,64] bf16 activations, in sorted-slot order
  size_t off = (size_t)E * 64 * 2;
  float* stats = (float*)(wsb + off);
  off += 1024 * 4;
  u32* bucketTotal = (u32*)(wsb + off);
  off += (NBMAX + 1) * 4;
  u32* baseArr = (u32*)(wsb + off);
  off += (NBMAX + 1) * 4;
  u32* cursor = (u32*)(wsb + off);
  off += NBMAX * 4;
  off = (off + 7) & ~(size_t)7;  // 8-align for uint2
  uint2* sorted2 = (uint2*)(wsb + off);
  off += (size_t)E * 8;
  u8* ln8 = (u8*)(wsb + off);
  off += (size_t)E;
  size_t need = off;

  float* gsum1 = stats + 64, * gsq1 = stats + 128;
  float* gsum2 = stats + 192, * gsq2 = stats + 256;
  float* gsum3 = stats + 320, * gsq3 = stats + 384;

  float* outf = (float*)d_out;
  float invE = 1.0f / (float)E;
  bool binned = (ws_size >= need) && (NB <= NBMAX);

  if (binned) {
    k_init<<<1, 1024, 0, stream>>>(stats, bucketTotal);
    k_norm_hist<<<256, 256, 0, stream>>>(ei, pos, E, NB, stats, bucketTotal);
    k_scan<<<1, 64, 0, stream>>>(bucketTotal, baseArr, cursor, NB);
    k_place<<<256, 256, 0, stream>>>(ei, E, NB, cursor, sorted2, ln8);
    k_layer1<<<1024, 256, 0, stream>>>(ei, pos, x, W1, b1, h, stats, gsum1, gsq1, E, sorted2);
    k_layer_mfma<<<1024, 256, 0, stream>>>(h, W2, b2, gsum1, gsq1, g1, be1, invE, gsum2, gsq2, E);
    k_layer_mfma<<<1024, 256, 0, stream>>>(h, W3, b3, gsum2, gsq2, g2, be2, invE, gsum3, gsq3, E);
    k_bucket_max<<<NB, 256, 0, stream>>>(ln8, baseArr, h, gsum3, gsq3, g3, be3, invE, outf, N);
  } else {
    k_initout<<<4096, 256, 0, stream>>>(outf, n_out, stats, bucketTotal);
    k_norm_hist<<<256, 256, 0, stream>>>(ei, pos, E, NB <= NBMAX ? NB : 1, stats, bucketTotal);
    k_layer1<<<1024, 256, 0, stream>>>(ei, pos, x, W1, b1, h, stats, gsum1, gsq1, E, (const uint2*)nullptr);
    k_layer_mfma<<<1024, 256, 0, stream>>>(h, W2, b2, gsum1, gsq1, g1, be1, invE, gsum2, gsq2, E);
    k_layer_mfma<<<1024, 256, 0, stream>>>(h, W3, b3, gsum2, gsq2, g2, be2, invE, gsum3, gsq3, E);
    k_scatter<<<2048, 256, 0, stream>>>(ei, h, gsum3, gsq3, g3, be3, invE, outf, E);
    k_out<<<2048, 256, 0, stream>>>(outf, n_out);
  }
}